// Round 4
// baseline (173.936 us; speedup 1.0000x reference)
//
#include <hip/hip_runtime.h>

typedef unsigned short u16;
typedef __bf16 v8bf __attribute__((ext_vector_type(8)));
typedef float f32x4 __attribute__((ext_vector_type(4)));
typedef u16 us8 __attribute__((ext_vector_type(8)));
typedef u16 us4 __attribute__((ext_vector_type(4)));

static __device__ __forceinline__ u16 f2bf(float f) {
  union { __bf16 h; u16 u; } cv;
  cv.h = (__bf16)f;
  return cv.u;
}

static __device__ __forceinline__ void gl_lds16(const u16* g, u16* l) {
  __builtin_amdgcn_global_load_lds(
      (const __attribute__((address_space(1))) unsigned int*)g,
      (__attribute__((address_space(3))) unsigned int*)l, 16, 0, 0);
}

// ---- adj fp32 -> adj_bf (row-major) + adjT_bf (transposed), 64x64 tiles.
//      Block (0,0,0) also folds W -> Mb: M[o][3c]=W0-W2, M[o][3c+1]=W1, M[o][3c+2]=W2
//      (the Chebyshev factor 2 is folded into adj2 instead). ----
__global__ __launch_bounds__(256)
void cvt_adjT_foldw_k(const float* __restrict__ adj, u16* __restrict__ adj_bf,
                      u16* __restrict__ adjT_bf, const float* __restrict__ W,
                      u16* __restrict__ Mb) {
  const int c0 = blockIdx.x * 64;
  const int r0 = blockIdx.y * 64;
  const int b = blockIdx.z;
  __shared__ u16 Ls[64][68];
  const int tid = threadIdx.x;
#pragma unroll
  for (int i = 0; i < 4; ++i) {
    const int idx = tid + 256 * i;          // 1024 float4 chunks (64 x 16)
    const int r = idx >> 4;
    const int c4 = (idx & 15) * 4;
    const float4 v = *(const float4*)(adj + ((size_t)(b * 512 + r0 + r) * 512 + c0 + c4));
    us4 o;
    o[0] = f2bf(v.x); o[1] = f2bf(v.y); o[2] = f2bf(v.z); o[3] = f2bf(v.w);
    *(us4*)&Ls[r][c4] = o;
    *(us4*)(adj_bf + ((size_t)(b * 512 + r0 + r) * 512 + c0 + c4)) = o;
  }
  __syncthreads();
#pragma unroll
  for (int i = 0; i < 2; ++i) {
    const int idx = tid + 256 * i;          // 512 us8 chunks (64 cols x 8)
    const int c = idx >> 3;                 // local col of adj
    const int r8 = (idx & 7) * 8;
    us8 o;
#pragma unroll
    for (int j = 0; j < 8; ++j) o[j] = Ls[r8 + j][c];
    *(us8*)(adjT_bf + ((size_t)(b * 512 + c0 + c) * 512 + r0 + r8)) = o;
  }
  if (blockIdx.x == 0 && blockIdx.y == 0 && blockIdx.z == 0) {
    for (int i = tid; i < 64 * 96; i += 256) {
      const int cc = i % 96;
      const int r = cc % 3;
      const float w = W[i];
      const float m = (r == 0) ? (w - W[i + 2]) : w;
      Mb[i] = f2bf(m);
    }
  }
}

// ---- x [b][q][j=c*64+l] fp32 -> xT [b][j][q] bf16 (64x64 LDS transpose) ----
__global__ __launch_bounds__(256)
void cvtT_x_k(const float* __restrict__ x, u16* __restrict__ xT) {
  const int j0 = blockIdx.x * 64;
  const int q0 = blockIdx.y * 64;
  const int b = blockIdx.z;
  __shared__ u16 Ls[64][68];
  const int tid = threadIdx.x;
#pragma unroll
  for (int i = 0; i < 4; ++i) {
    const int idx = tid + 256 * i;
    const int r = idx >> 4;
    const int j4 = (idx & 15) * 4;
    const float4 v = *(const float4*)(x + ((size_t)(b * 512 + q0 + r) * 2048 + j0 + j4));
    us4 o;
    o[0] = f2bf(v.x); o[1] = f2bf(v.y); o[2] = f2bf(v.z); o[3] = f2bf(v.w);
    *(us4*)&Ls[r][j4] = o;
  }
  __syncthreads();
#pragma unroll
  for (int i = 0; i < 2; ++i) {
    const int idx = tid + 256 * i;
    const int jp = idx >> 3;
    const int q8 = (idx & 7) * 8;
    us8 o;
#pragma unroll
    for (int j = 0; j < 8; ++j) o[j] = Ls[q8 + j][jp];
    *(us8*)(xT + ((size_t)(b * 2048 + j0 + jp) * 512 + q0 + q8)) = o;
  }
}

// ---- adj2[b] = 2 * adj[b] @ adj[b]  (512x512x512, bf16 out) ----
__global__ __launch_bounds__(256)
void gemm_sq(const u16* __restrict__ A, const u16* __restrict__ BT,
             u16* __restrict__ C) {
  const int b = blockIdx.z;
  const int row0 = blockIdx.y * 128;
  const int col0 = blockIdx.x * 128;
  const u16* Ab = A + (size_t)b * 512 * 512;
  const u16* BTb = BT + (size_t)b * 512 * 512;

  __shared__ u16 smem[16384];
  u16* As = smem;              // [128][64] linear
  u16* Bs = smem + 8192;

  const int tid = threadIdx.x;
  const int lane = tid & 63;
  const int w = tid >> 6;
  const int wm = (w >> 1) * 64;
  const int wn = (w & 1) * 64;
  const int l16 = lane & 15;
  const int kg = lane >> 4;

  f32x4 acc[4][4];
#pragma unroll
  for (int m = 0; m < 4; ++m)
#pragma unroll
    for (int n = 0; n < 4; ++n) acc[m][n] = (f32x4){0.f, 0.f, 0.f, 0.f};

  for (int k0 = 0; k0 < 512; k0 += 64) {
    __syncthreads();
#pragma unroll
    for (int i = 0; i < 4; ++i) {
      const int eb = w * 2048 + i * 512;
      const int e = eb + lane * 8;
      const int r = e >> 6;
      const int kk = e & 63;
      gl_lds16(Ab + (size_t)(row0 + r) * 512 + k0 + kk, As + eb);
      gl_lds16(BTb + (size_t)(col0 + r) * 512 + k0 + kk, Bs + eb);
    }
    __syncthreads();
#pragma unroll
    for (int ks = 0; ks < 2; ++ks) {
      v8bf af[4], bfr[4];
#pragma unroll
      for (int m = 0; m < 4; ++m)
        af[m] = *(const v8bf*)(As + (wm + m * 16 + l16) * 64 + ks * 32 + kg * 8);
#pragma unroll
      for (int n = 0; n < 4; ++n)
        bfr[n] = *(const v8bf*)(Bs + (wn + n * 16 + l16) * 64 + ks * 32 + kg * 8);
#pragma unroll
      for (int m = 0; m < 4; ++m)
#pragma unroll
        for (int n = 0; n < 4; ++n)
          acc[m][n] = __builtin_amdgcn_mfma_f32_16x16x32_bf16(af[m], bfr[n], acc[m][n], 0, 0, 0);
    }
  }
  u16* Cb = C + (size_t)b * 512 * 512;
#pragma unroll
  for (int m = 0; m < 4; ++m)
#pragma unroll
    for (int n = 0; n < 4; ++n)
#pragma unroll
      for (int v = 0; v < 4; ++v) {
        const int rr = row0 + wm + m * 16 + kg * 4 + v;
        const int cc = col0 + wn + n * 16 + l16;
        Cb[(size_t)rr * 512 + cc] = f2bf(2.0f * acc[m][n][v]);
      }
}

// ---- fused propagate: X1[b]=adj@X, Y2[b]=adj2@X (B-tile staged ONCE) ----
__global__ __launch_bounds__(256)
void prop_k(const u16* __restrict__ A1, const u16* __restrict__ A2,
            const u16* __restrict__ BT, u16* __restrict__ X1,
            u16* __restrict__ Y2) {
  const int b = blockIdx.z;
  const int row0 = blockIdx.y * 128;
  const int col0 = blockIdx.x * 128;
  const u16* A1b = A1 + (size_t)b * 512 * 512;
  const u16* A2b = A2 + (size_t)b * 512 * 512;
  const u16* BTb = BT + (size_t)b * 2048 * 512;

  __shared__ u16 smem[24576];  // 48 KB
  u16* As1 = smem;             // [128][64]
  u16* As2 = smem + 8192;
  u16* Bs  = smem + 16384;

  const int tid = threadIdx.x;
  const int lane = tid & 63;
  const int w = tid >> 6;
  const int wm = (w >> 1) * 64;
  const int wn = (w & 1) * 64;
  const int l16 = lane & 15;
  const int kg = lane >> 4;

  f32x4 accA[4][4], accB[4][4];
#pragma unroll
  for (int m = 0; m < 4; ++m)
#pragma unroll
    for (int n = 0; n < 4; ++n) {
      accA[m][n] = (f32x4){0.f, 0.f, 0.f, 0.f};
      accB[m][n] = (f32x4){0.f, 0.f, 0.f, 0.f};
    }

  for (int k0 = 0; k0 < 512; k0 += 64) {
    __syncthreads();
#pragma unroll
    for (int i = 0; i < 4; ++i) {
      const int eb = w * 2048 + i * 512;    // wave-uniform LDS elem base
      const int e = eb + lane * 8;
      const int r = e >> 6;
      const int kk = e & 63;
      gl_lds16(A1b + (size_t)(row0 + r) * 512 + k0 + kk, As1 + eb);
      gl_lds16(A2b + (size_t)(row0 + r) * 512 + k0 + kk, As2 + eb);
      gl_lds16(BTb + (size_t)(col0 + r) * 512 + k0 + kk, Bs + eb);
    }
    __syncthreads();
#pragma unroll
    for (int ks = 0; ks < 2; ++ks) {
      v8bf bfr[4], af[4];
#pragma unroll
      for (int n = 0; n < 4; ++n)
        bfr[n] = *(const v8bf*)(Bs + (wn + n * 16 + l16) * 64 + ks * 32 + kg * 8);
#pragma unroll
      for (int m = 0; m < 4; ++m)
        af[m] = *(const v8bf*)(As1 + (wm + m * 16 + l16) * 64 + ks * 32 + kg * 8);
#pragma unroll
      for (int m = 0; m < 4; ++m)
#pragma unroll
        for (int n = 0; n < 4; ++n)
          accA[m][n] = __builtin_amdgcn_mfma_f32_16x16x32_bf16(af[m], bfr[n], accA[m][n], 0, 0, 0);
#pragma unroll
      for (int m = 0; m < 4; ++m)
        af[m] = *(const v8bf*)(As2 + (wm + m * 16 + l16) * 64 + ks * 32 + kg * 8);
#pragma unroll
      for (int m = 0; m < 4; ++m)
#pragma unroll
        for (int n = 0; n < 4; ++n)
          accB[m][n] = __builtin_amdgcn_mfma_f32_16x16x32_bf16(af[m], bfr[n], accB[m][n], 0, 0, 0);
    }
  }

  u16* X1b = X1 + (size_t)b * 512 * 2048;
  u16* Y2b = Y2 + (size_t)b * 512 * 2048;
#pragma unroll
  for (int m = 0; m < 4; ++m)
#pragma unroll
    for (int n = 0; n < 4; ++n)
#pragma unroll
      for (int v = 0; v < 4; ++v) {
        const int rr = row0 + wm + m * 16 + kg * 4 + v;
        const int cc = col0 + wn + n * 16 + l16;
        X1b[(size_t)rr * 2048 + cc] = f2bf(accA[m][n][v]);
        Y2b[(size_t)rr * 2048 + cc] = f2bf(accB[m][n][v]);
      }
}

// ---- mix (unchanged): per (b,q): out[b,:,q,:] = M(64x96) @ V(96x64) + bias ----
__global__ __launch_bounds__(256)
void mix_mfma(const float* __restrict__ x0, const u16* __restrict__ x1,
              const u16* __restrict__ y2, const u16* __restrict__ Mb,
              const float* __restrict__ bias, float* __restrict__ out) {
  const int q = blockIdx.x;
  const int b = blockIdx.y;
  __shared__ u16 Vt[64][104];
  __shared__ u16 Ms[64][104];
  const int tid = threadIdx.x;
  const int lane = tid & 63;
  const int w = tid >> 6;
  const int l16 = lane & 15;
  const int kg = lane >> 4;

#pragma unroll
  for (int i = 0; i < 3; ++i) {
    const int idx = tid + 256 * i;
    const int o = idx / 12;
    const int c8 = (idx % 12) * 8;
    *(uint4*)&Ms[o][c8] = *(const uint4*)(Mb + o * 96 + c8);
  }
  const size_t base = ((size_t)b * 512 + q) * 2048;
#pragma unroll
  for (int i = 0; i < 2; ++i) {
    const int idx = tid + 256 * i;
    const int c = idx >> 4;
    const int l0 = (idx & 15) * 4;
    const float4 v = *(const float4*)(x0 + base + c * 64 + l0);
    Vt[l0 + 0][3 * c] = f2bf(v.x);
    Vt[l0 + 1][3 * c] = f2bf(v.y);
    Vt[l0 + 2][3 * c] = f2bf(v.z);
    Vt[l0 + 3][3 * c] = f2bf(v.w);
  }
  {
    const int c = tid >> 3;
    const int l0 = (tid & 7) * 8;
    const us8 v1 = *(const us8*)(x1 + base + c * 64 + l0);
    const us8 v2 = *(const us8*)(y2 + base + c * 64 + l0);
#pragma unroll
    for (int j = 0; j < 8; ++j) {
      Vt[l0 + j][3 * c + 1] = v1[j];
      Vt[l0 + j][3 * c + 2] = v2[j];
    }
  }
  __syncthreads();

  f32x4 acc[4];
#pragma unroll
  for (int n = 0; n < 4; ++n) acc[n] = (f32x4){0.f, 0.f, 0.f, 0.f};
#pragma unroll
  for (int ks = 0; ks < 3; ++ks) {
    const v8bf a = *(const v8bf*)&Ms[w * 16 + l16][ks * 32 + kg * 8];
#pragma unroll
    for (int n = 0; n < 4; ++n) {
      const v8bf bv = *(const v8bf*)&Vt[n * 16 + l16][ks * 32 + kg * 8];
      acc[n] = __builtin_amdgcn_mfma_f32_16x16x32_bf16(a, bv, acc[n], 0, 0, 0);
    }
  }
#pragma unroll
  for (int n = 0; n < 4; ++n)
#pragma unroll
    for (int v = 0; v < 4; ++v) {
      const int o = w * 16 + kg * 4 + v;
      out[(((size_t)b * 64 + o) * 512 + q) * 64 + n * 16 + l16] = acc[n][v] + bias[o];
    }
}

extern "C" void kernel_launch(void* const* d_in, const int* in_sizes, int n_in,
                              void* d_out, int out_size, void* d_ws, size_t ws_size,
                              hipStream_t stream) {
  const float* x   = (const float*)d_in[0];  // [16,512,32,64]
  const float* adj = (const float*)d_in[1];  // [16,512,512]
  const float* W   = (const float*)d_in[2];  // [64,96]
  const float* bia = (const float*)d_in[3];  // [64]
  float* out = (float*)d_out;                // [16,64,512,64]

  u16* adj_bf  = (u16*)d_ws;                              // 8.4 MB
  u16* adjT_bf = adj_bf  + (size_t)16 * 512 * 512;
  u16* adj2_bf = adjT_bf + (size_t)16 * 512 * 512;
  u16* xT      = adj2_bf + (size_t)16 * 512 * 512;        // [16][2048][512]
  u16* X1      = xT      + (size_t)16 * 2048 * 512;       // [16][512][2048]
  u16* Y2      = X1      + (size_t)16 * 512 * 2048;
  u16* Mb      = Y2      + (size_t)16 * 512 * 2048;

  hipLaunchKernelGGL(cvt_adjT_foldw_k, dim3(8, 8, 16), dim3(256), 0, stream,
                     adj, adj_bf, adjT_bf, W, Mb);
  hipLaunchKernelGGL(cvtT_x_k, dim3(32, 8, 16), dim3(256), 0, stream, x, xT);
  hipLaunchKernelGGL(gemm_sq, dim3(4, 4, 16), dim3(256), 0, stream,
                     adj_bf, adjT_bf, adj2_bf);
  hipLaunchKernelGGL(prop_k, dim3(16, 4, 16), dim3(256), 0, stream,
                     adj_bf, adj2_bf, xT, X1, Y2);
  hipLaunchKernelGGL(mix_mfma, dim3(512, 16), dim3(256), 0, stream,
                     x, X1, Y2, Mb, bia, out);
}

// Round 5
// 152.813 us; speedup vs baseline: 1.1382x; 1.1382x over previous
//
#include <hip/hip_runtime.h>

typedef unsigned short u16;
typedef __bf16 v8bf __attribute__((ext_vector_type(8)));
typedef float f32x4 __attribute__((ext_vector_type(4)));
typedef u16 us8 __attribute__((ext_vector_type(8)));
typedef u16 us4 __attribute__((ext_vector_type(4)));

static __device__ __forceinline__ u16 f2bf(float f) {
  union { __bf16 h; u16 u; } cv;
  cv.h = (__bf16)f;
  return cv.u;
}

static __device__ __forceinline__ void gl_lds16(const u16* g, u16* l) {
  __builtin_amdgcn_global_load_lds(
      (const __attribute__((address_space(1))) unsigned int*)g,
      (__attribute__((address_space(3))) unsigned int*)l, 16, 0, 0);
}

// ---- adj fp32 -> adj_bf (row-major) + adjT_bf (transposed), 64x64 tiles.
//      Block (0,0,0) also folds W -> Mb (factor 2 folded into adj2). ----
__global__ __launch_bounds__(256)
void cvt_adjT_foldw_k(const float* __restrict__ adj, u16* __restrict__ adj_bf,
                      u16* __restrict__ adjT_bf, const float* __restrict__ W,
                      u16* __restrict__ Mb) {
  const int c0 = blockIdx.x * 64;
  const int r0 = blockIdx.y * 64;
  const int b = blockIdx.z;
  __shared__ u16 Ls[64][68];
  const int tid = threadIdx.x;
#pragma unroll
  for (int i = 0; i < 4; ++i) {
    const int idx = tid + 256 * i;          // 1024 float4 chunks (64 x 16)
    const int r = idx >> 4;
    const int c4 = (idx & 15) * 4;
    const float4 v = *(const float4*)(adj + ((size_t)(b * 512 + r0 + r) * 512 + c0 + c4));
    us4 o;
    o[0] = f2bf(v.x); o[1] = f2bf(v.y); o[2] = f2bf(v.z); o[3] = f2bf(v.w);
    *(us4*)&Ls[r][c4] = o;
    *(us4*)(adj_bf + ((size_t)(b * 512 + r0 + r) * 512 + c0 + c4)) = o;
  }
  __syncthreads();
#pragma unroll
  for (int i = 0; i < 2; ++i) {
    const int idx = tid + 256 * i;          // 512 us8 chunks (64 cols x 8)
    const int c = idx >> 3;                 // local col of adj
    const int r8 = (idx & 7) * 8;
    us8 o;
#pragma unroll
    for (int j = 0; j < 8; ++j) o[j] = Ls[r8 + j][c];
    *(us8*)(adjT_bf + ((size_t)(b * 512 + c0 + c) * 512 + r0 + r8)) = o;
  }
  if (blockIdx.x == 0 && blockIdx.y == 0 && blockIdx.z == 0) {
    for (int i = tid; i < 64 * 96; i += 256) {
      const int cc = i % 96;
      const int r = cc % 3;
      const float w = W[i];
      const float m = (r == 0) ? (w - W[i + 2]) : w;
      Mb[i] = f2bf(m);
    }
  }
}

// ---- x [b][q][j=c*64+l] fp32 -> xT [b][j][q] bf16 (64x64 LDS transpose) ----
__global__ __launch_bounds__(256)
void cvtT_x_k(const float* __restrict__ x, u16* __restrict__ xT) {
  const int j0 = blockIdx.x * 64;
  const int q0 = blockIdx.y * 64;
  const int b = blockIdx.z;
  __shared__ u16 Ls[64][68];
  const int tid = threadIdx.x;
#pragma unroll
  for (int i = 0; i < 4; ++i) {
    const int idx = tid + 256 * i;
    const int r = idx >> 4;
    const int j4 = (idx & 15) * 4;
    const float4 v = *(const float4*)(x + ((size_t)(b * 512 + q0 + r) * 2048 + j0 + j4));
    us4 o;
    o[0] = f2bf(v.x); o[1] = f2bf(v.y); o[2] = f2bf(v.z); o[3] = f2bf(v.w);
    *(us4*)&Ls[r][j4] = o;
  }
  __syncthreads();
#pragma unroll
  for (int i = 0; i < 2; ++i) {
    const int idx = tid + 256 * i;
    const int jp = idx >> 3;
    const int q8 = (idx & 7) * 8;
    us8 o;
#pragma unroll
    for (int j = 0; j < 8; ++j) o[j] = Ls[q8 + j][jp];
    *(us8*)(xT + ((size_t)(b * 2048 + j0 + jp) * 512 + q0 + q8)) = o;
  }
}

// ---- adj2[b] = 2 * adj[b] @ adj[b]  (512x512x512, bf16 out) ----
__global__ __launch_bounds__(256)
void gemm_sq(const u16* __restrict__ A, const u16* __restrict__ BT,
             u16* __restrict__ C) {
  const int b = blockIdx.z;
  const int row0 = blockIdx.y * 128;
  const int col0 = blockIdx.x * 128;
  const u16* Ab = A + (size_t)b * 512 * 512;
  const u16* BTb = BT + (size_t)b * 512 * 512;

  __shared__ u16 smem[16384];
  u16* As = smem;              // [128][64] linear
  u16* Bs = smem + 8192;

  const int tid = threadIdx.x;
  const int lane = tid & 63;
  const int w = tid >> 6;
  const int wm = (w >> 1) * 64;
  const int wn = (w & 1) * 64;
  const int l16 = lane & 15;
  const int kg = lane >> 4;

  f32x4 acc[4][4];
#pragma unroll
  for (int m = 0; m < 4; ++m)
#pragma unroll
    for (int n = 0; n < 4; ++n) acc[m][n] = (f32x4){0.f, 0.f, 0.f, 0.f};

  for (int k0 = 0; k0 < 512; k0 += 64) {
    __syncthreads();
#pragma unroll
    for (int i = 0; i < 4; ++i) {
      const int eb = w * 2048 + i * 512;
      const int e = eb + lane * 8;
      const int r = e >> 6;
      const int kk = e & 63;
      gl_lds16(Ab + (size_t)(row0 + r) * 512 + k0 + kk, As + eb);
      gl_lds16(BTb + (size_t)(col0 + r) * 512 + k0 + kk, Bs + eb);
    }
    __syncthreads();
#pragma unroll
    for (int ks = 0; ks < 2; ++ks) {
      v8bf af[4], bfr[4];
#pragma unroll
      for (int m = 0; m < 4; ++m)
        af[m] = *(const v8bf*)(As + (wm + m * 16 + l16) * 64 + ks * 32 + kg * 8);
#pragma unroll
      for (int n = 0; n < 4; ++n)
        bfr[n] = *(const v8bf*)(Bs + (wn + n * 16 + l16) * 64 + ks * 32 + kg * 8);
#pragma unroll
      for (int m = 0; m < 4; ++m)
#pragma unroll
        for (int n = 0; n < 4; ++n)
          acc[m][n] = __builtin_amdgcn_mfma_f32_16x16x32_bf16(af[m], bfr[n], acc[m][n], 0, 0, 0);
    }
  }
  u16* Cb = C + (size_t)b * 512 * 512;
#pragma unroll
  for (int m = 0; m < 4; ++m)
#pragma unroll
    for (int n = 0; n < 4; ++n)
#pragma unroll
      for (int v = 0; v < 4; ++v) {
        const int rr = row0 + wm + m * 16 + kg * 4 + v;
        const int cc = col0 + wn + n * 16 + l16;
        Cb[(size_t)rr * 512 + cc] = f2bf(2.0f * acc[m][n][v]);
      }
}

// ---- fused propagate, 8-wave split: waves 0-3 -> X1 = adj@X quadrants,
//      waves 4-7 -> Y2 = adj2@X quadrants. B-tile staged once, shared.
//      Per-wave acc = 64 f32 (keeps VGPR ~120 -> 4 waves/SIMD). ----
__global__ __launch_bounds__(512, 4)
void prop_k(const u16* __restrict__ A1, const u16* __restrict__ A2,
            const u16* __restrict__ BT, u16* __restrict__ X1,
            u16* __restrict__ Y2) {
  const int b = blockIdx.z;
  const int row0 = blockIdx.y * 128;
  const int col0 = blockIdx.x * 128;
  const u16* A1b = A1 + (size_t)b * 512 * 512;
  const u16* A2b = A2 + (size_t)b * 512 * 512;
  const u16* BTb = BT + (size_t)b * 2048 * 512;

  __shared__ u16 smem[24576];  // 48 KB
  u16* As1 = smem;             // [128][64] linear
  u16* As2 = smem + 8192;
  u16* Bs  = smem + 16384;

  const int tid = threadIdx.x;
  const int lane = tid & 63;
  const int w = tid >> 6;         // 0..7
  const int wq = w & 3;           // quadrant
  const int wm = (wq >> 1) * 64;
  const int wn = (wq & 1) * 64;
  const int l16 = lane & 15;
  const int kg = lane >> 4;

  f32x4 acc[4][4];
#pragma unroll
  for (int m = 0; m < 4; ++m)
#pragma unroll
    for (int n = 0; n < 4; ++n) acc[m][n] = (f32x4){0.f, 0.f, 0.f, 0.f};

  for (int k0 = 0; k0 < 512; k0 += 64) {
    __syncthreads();
    // 48 chunks of 1KB (16 per tile); each of the 8 waves stages 2 per tile
#pragma unroll
    for (int i = 0; i < 2; ++i) {
      const int eb = w * 1024 + i * 512;    // wave-uniform LDS elem base
      const int e = eb + lane * 8;
      const int r = e >> 6;
      const int kk = e & 63;
      gl_lds16(A1b + (size_t)(row0 + r) * 512 + k0 + kk, As1 + eb);
      gl_lds16(A2b + (size_t)(row0 + r) * 512 + k0 + kk, As2 + eb);
      gl_lds16(BTb + (size_t)(col0 + r) * 512 + k0 + kk, Bs + eb);
    }
    __syncthreads();
    const u16* Asrc = (w < 4) ? As1 : As2;
#pragma unroll
    for (int ks = 0; ks < 2; ++ks) {
      v8bf af[4], bfr[4];
#pragma unroll
      for (int m = 0; m < 4; ++m)
        af[m] = *(const v8bf*)(Asrc + (wm + m * 16 + l16) * 64 + ks * 32 + kg * 8);
#pragma unroll
      for (int n = 0; n < 4; ++n)
        bfr[n] = *(const v8bf*)(Bs + (wn + n * 16 + l16) * 64 + ks * 32 + kg * 8);
#pragma unroll
      for (int m = 0; m < 4; ++m)
#pragma unroll
        for (int n = 0; n < 4; ++n)
          acc[m][n] = __builtin_amdgcn_mfma_f32_16x16x32_bf16(af[m], bfr[n], acc[m][n], 0, 0, 0);
    }
  }

  u16* Db = ((w < 4) ? X1 : Y2) + (size_t)b * 512 * 2048;
#pragma unroll
  for (int m = 0; m < 4; ++m)
#pragma unroll
    for (int n = 0; n < 4; ++n)
#pragma unroll
      for (int v = 0; v < 4; ++v) {
        const int rr = row0 + wm + m * 16 + kg * 4 + v;
        const int cc = col0 + wn + n * 16 + l16;
        Db[(size_t)rr * 2048 + cc] = f2bf(acc[m][n][v]);
      }
}

// ---- mix (unchanged): per (b,q): out[b,:,q,:] = M(64x96) @ V(96x64) + bias ----
__global__ __launch_bounds__(256)
void mix_mfma(const float* __restrict__ x0, const u16* __restrict__ x1,
              const u16* __restrict__ y2, const u16* __restrict__ Mb,
              const float* __restrict__ bias, float* __restrict__ out) {
  const int q = blockIdx.x;
  const int b = blockIdx.y;
  __shared__ u16 Vt[64][104];
  __shared__ u16 Ms[64][104];
  const int tid = threadIdx.x;
  const int lane = tid & 63;
  const int w = tid >> 6;
  const int l16 = lane & 15;
  const int kg = lane >> 4;

#pragma unroll
  for (int i = 0; i < 3; ++i) {
    const int idx = tid + 256 * i;
    const int o = idx / 12;
    const int c8 = (idx % 12) * 8;
    *(uint4*)&Ms[o][c8] = *(const uint4*)(Mb + o * 96 + c8);
  }
  const size_t base = ((size_t)b * 512 + q) * 2048;
#pragma unroll
  for (int i = 0; i < 2; ++i) {
    const int idx = tid + 256 * i;
    const int c = idx >> 4;
    const int l0 = (idx & 15) * 4;
    const float4 v = *(const float4*)(x0 + base + c * 64 + l0);
    Vt[l0 + 0][3 * c] = f2bf(v.x);
    Vt[l0 + 1][3 * c] = f2bf(v.y);
    Vt[l0 + 2][3 * c] = f2bf(v.z);
    Vt[l0 + 3][3 * c] = f2bf(v.w);
  }
  {
    const int c = tid >> 3;
    const int l0 = (tid & 7) * 8;
    const us8 v1 = *(const us8*)(x1 + base + c * 64 + l0);
    const us8 v2 = *(const us8*)(y2 + base + c * 64 + l0);
#pragma unroll
    for (int j = 0; j < 8; ++j) {
      Vt[l0 + j][3 * c + 1] = v1[j];
      Vt[l0 + j][3 * c + 2] = v2[j];
    }
  }
  __syncthreads();

  f32x4 acc[4];
#pragma unroll
  for (int n = 0; n < 4; ++n) acc[n] = (f32x4){0.f, 0.f, 0.f, 0.f};
#pragma unroll
  for (int ks = 0; ks < 3; ++ks) {
    const v8bf a = *(const v8bf*)&Ms[w * 16 + l16][ks * 32 + kg * 8];
#pragma unroll
    for (int n = 0; n < 4; ++n) {
      const v8bf bv = *(const v8bf*)&Vt[n * 16 + l16][ks * 32 + kg * 8];
      acc[n] = __builtin_amdgcn_mfma_f32_16x16x32_bf16(a, bv, acc[n], 0, 0, 0);
    }
  }
#pragma unroll
  for (int n = 0; n < 4; ++n)
#pragma unroll
    for (int v = 0; v < 4; ++v) {
      const int o = w * 16 + kg * 4 + v;
      out[(((size_t)b * 64 + o) * 512 + q) * 64 + n * 16 + l16] = acc[n][v] + bias[o];
    }
}

extern "C" void kernel_launch(void* const* d_in, const int* in_sizes, int n_in,
                              void* d_out, int out_size, void* d_ws, size_t ws_size,
                              hipStream_t stream) {
  const float* x   = (const float*)d_in[0];  // [16,512,32,64]
  const float* adj = (const float*)d_in[1];  // [16,512,512]
  const float* W   = (const float*)d_in[2];  // [64,96]
  const float* bia = (const float*)d_in[3];  // [64]
  float* out = (float*)d_out;                // [16,64,512,64]

  u16* adj_bf  = (u16*)d_ws;                              // 8.4 MB
  u16* adjT_bf = adj_bf  + (size_t)16 * 512 * 512;
  u16* adj2_bf = adjT_bf + (size_t)16 * 512 * 512;
  u16* xT      = adj2_bf + (size_t)16 * 512 * 512;        // [16][2048][512]
  u16* X1      = xT      + (size_t)16 * 2048 * 512;       // [16][512][2048]
  u16* Y2      = X1      + (size_t)16 * 512 * 2048;
  u16* Mb      = Y2      + (size_t)16 * 512 * 2048;

  hipLaunchKernelGGL(cvt_adjT_foldw_k, dim3(8, 8, 16), dim3(256), 0, stream,
                     adj, adj_bf, adjT_bf, W, Mb);
  hipLaunchKernelGGL(cvtT_x_k, dim3(32, 8, 16), dim3(256), 0, stream, x, xT);
  hipLaunchKernelGGL(gemm_sq, dim3(4, 4, 16), dim3(256), 0, stream,
                     adj_bf, adjT_bf, adj2_bf);
  hipLaunchKernelGGL(prop_k, dim3(16, 4, 16), dim3(512), 0, stream,
                     adj_bf, adj2_bf, xT, X1, Y2);
  hipLaunchKernelGGL(mix_mfma, dim3(512, 16), dim3(256), 0, stream,
                     x, X1, Y2, Mb, bia, out);
}